// Round 3
// baseline (529.633 us; speedup 1.0000x reference)
//
#include <hip/hip_runtime.h>
#include <hip/hip_bf16.h>
#include <math.h>

// Problem constants: N=100000, K=10, T=7, D=7, O=32
#define T_ 7
#define D_ 7
#define K_ 10
#define O_ 32
#define NPB 128           // nodes per block (== blockDim.x)
#define NREP 16           // replicated global accumulators (atomic spread)
#define NEG_SLOPE 0.01f

// ---------------- K0: zero the replicated output accumulators --------------
__global__ void k0_zero(float* __restrict__ acc) {
    int i = threadIdx.x;
    if (i < NREP * O_) acc[i] = 0.f;
}

// ---------------- fused kernel --------------------------------------------
// One block = 128 nodes. t-loop: fully-unrolled predicated float4 loads into
// registers (all 18 issued before any wait -> one latency exposure per tile),
// barrier, ds_write, barrier, compute. h[56] in registers. Epilogue GEMM from
// LDS W_agg, sigmoid, wave shuffle-reduce, replicated global atomics.
__global__ __launch_bounds__(NPB) void k_fused(
    const float* __restrict__ xhet,   // [T,N,K,D]
    const float* __restrict__ xnode,  // [N,D]
    const int*   __restrict__ types,  // [N]
    const float* __restrict__ Wc,     // [T,D,D]
    const float* __restrict__ bc,     // [T,D]
    const float* __restrict__ Wagg,   // [O,56]
    const float* __restrict__ bagg,   // [O]
    float* __restrict__ acc_out,      // [NREP][O] global accumulators
    int N)
{
    __shared__ __align__(16) float tile[NPB * 70];   // 35840 B
    __shared__ float4 sW[O_ * 14];                   // 7168 B
    __shared__ float  sb[O_];
    __shared__ float  sacc[O_];
    // total ~43.4 KB -> 3 blocks/CU

    const int tx = threadIdx.x;
    const int nodeBase = blockIdx.x * NPB;
    const int n = nodeBase + tx;
    const bool active = (n < N);
    const int valid = min(NPB, N - nodeBase);
    const int L  = valid * 70;        // floats in this block's tile
    const int L4 = L >> 2;            // full float4s (valid even -> L%4==0 for our N)

    // stage W_agg (1792 floats = 448 float4)
    for (int i = tx; i < O_ * 14; i += NPB) sW[i] = ((const float4*)Wagg)[i];
    if (tx < O_) { sb[tx] = bagg[tx]; sacc[tx] = 0.f; }

    // per-thread self inputs (tiny, L2/L3-resident)
    float x[D_]; int tp = -1;
    if (active) {
        tp = types[n];
        #pragma unroll
        for (int d = 0; d < D_; ++d) x[d] = xnode[(size_t)n * D_ + d];
    } else {
        #pragma unroll
        for (int d = 0; d < D_; ++d) x[d] = 0.f;
    }

    float h[(T_ + 1) * D_];           // concat layout: h[t*7+o], self at 49..55
    #pragma unroll
    for (int j = 0; j < (T_ + 1) * D_; ++j) h[j] = 0.f;

    for (int t = 0; t < T_; ++t) {
        // block-uniform weights -> scalar regs
        float w[D_][D_], bias[D_];
        #pragma unroll
        for (int o = 0; o < D_; ++o) {
            bias[o] = bc[t * D_ + o];
            #pragma unroll
            for (int d = 0; d < D_; ++d) w[o][d] = Wc[(t * D_ + o) * D_ + d];
        }

        const float*  src  = xhet + ((size_t)t * N + nodeBase) * 70;
        const float4* src4 = (const float4*)src;     // 16B-aligned (nodeBase%128==0)

        // ---- issue ALL tile loads back-to-back (predicated, fully unrolled)
        float4 r[18];                                 // 2240 float4 / 128 thr = 17.5
        #pragma unroll
        for (int j = 0; j < 18; ++j) {
            const int i = j * NPB + tx;
            if (i < L4) r[j] = src4[i];
        }

        __syncthreads();   // prev iteration's readers done before overwrite
        #pragma unroll
        for (int j = 0; j < 18; ++j) {
            const int i = j * NPB + tx;
            if (i < L4) ((float4*)tile)[i] = r[j];
        }
        for (int i = (L4 << 2) + tx; i < L; i += NPB) tile[i] = src[i]; // rare tail
        __syncthreads();

        if (active) {
            const float* myp = tile + tx * 70;
            float acc[D_] = {0.f, 0.f, 0.f, 0.f, 0.f, 0.f, 0.f};
            float cnt = 0.f;
            #pragma unroll
            for (int kk = 0; kk < K_ / 2; ++kk) {    // k in pairs: 14 floats = 7 float2
                float f[14];
                const float2* p2 = (const float2*)(myp + kk * 14);
                #pragma unroll
                for (int j = 0; j < 7; ++j) { float2 v = p2[j]; f[2*j] = v.x; f[2*j+1] = v.y; }
                #pragma unroll
                for (int hh = 0; hh < 2; ++hh) {
                    float pre[D_];
                    #pragma unroll
                    for (int o = 0; o < D_; ++o) pre[o] = bias[o];
                    #pragma unroll
                    for (int d = 0; d < D_; ++d) {
                        const float xv = f[hh * 7 + d];
                        #pragma unroll
                        for (int o = 0; o < D_; ++o) pre[o] = fmaf(xv, w[o][d], pre[o]);
                    }
                    bool nz = false;
                    #pragma unroll
                    for (int o = 0; o < D_; ++o) nz = nz || (pre[o] != 0.f);
                    cnt += nz ? 1.f : 0.f;
                    #pragma unroll
                    for (int o = 0; o < D_; ++o)
                        acc[o] += (pre[o] >= 0.f) ? pre[o] : NEG_SLOPE * pre[o];
                }
            }
            const float inv = 1.f / fmaxf(cnt, 1.f);
            #pragma unroll
            for (int o = 0; o < D_; ++o) h[t * D_ + o] = acc[o] * inv;

            // self candidate with this t's uniform weights; select on type match
            float ps[D_];
            #pragma unroll
            for (int o = 0; o < D_; ++o) {
                float p = bias[o];
                #pragma unroll
                for (int d = 0; d < D_; ++d) p = fmaf(x[d], w[o][d], p);
                ps[o] = (p >= 0.f) ? p : NEG_SLOPE * p;
            }
            if (tp == t) {
                #pragma unroll
                for (int o = 0; o < D_; ++o) h[T_ * D_ + o] = ps[o];
            }
        }
    }

    // ---- epilogue: [56] x [O,56]^T + bias -> sigmoid -> reduce
    const int lane = tx & 63;
    #pragma unroll 4
    for (int o = 0; o < O_; ++o) {
        float s = sb[o];
        #pragma unroll
        for (int q = 0; q < 14; ++q) {
            float4 wv = sW[o * 14 + q];
            s += h[4*q] * wv.x + h[4*q+1] * wv.y + h[4*q+2] * wv.z + h[4*q+3] * wv.w;
        }
        float val = active ? 1.f / (1.f + __expf(-s)) : 0.f;
        #pragma unroll
        for (int off = 32; off >= 1; off >>= 1) val += __shfl_down(val, off);
        if (lane == 0) atomicAdd(&sacc[o], val);
    }
    __syncthreads();
    if (tx < O_) atomicAdd(acc_out + (blockIdx.x & (NREP - 1)) * O_ + tx, sacc[tx]);
}

// ---------------- K3: sum replicas, divide by N into d_out -----------------
__global__ void k3_finish(const float* __restrict__ acc, float* __restrict__ out, float invN) {
    int o = threadIdx.x;
    if (o < O_) {
        float s = 0.f;
        #pragma unroll
        for (int rr = 0; rr < NREP; ++rr) s += acc[rr * O_ + o];
        out[o] = s * invN;
    }
}

extern "C" void kernel_launch(void* const* d_in, const int* in_sizes, int n_in,
                              void* d_out, int out_size, void* d_ws, size_t ws_size,
                              hipStream_t stream) {
    const float* xnode = (const float*)d_in[0];   // [N,D]
    const float* xhet  = (const float*)d_in[1];   // [T,N,K,D]
    const int*   types = (const int*)d_in[2];     // [N]
    const float* Wc    = (const float*)d_in[3];   // [T,D,D]
    const float* bc    = (const float*)d_in[4];   // [T,D]
    const float* Wagg  = (const float*)d_in[5];   // [O,56]
    const float* bagg  = (const float*)d_in[6];   // [O]
    float* out = (float*)d_out;

    const int N = in_sizes[2];
    float* acc_out = (float*)d_ws;                // NREP*32 floats

    const int nblk = (N + NPB - 1) / NPB;

    k0_zero<<<1, 512, 0, stream>>>(acc_out);
    k_fused<<<nblk, NPB, 0, stream>>>(xhet, xnode, types, Wc, bc, Wagg, bagg, acc_out, N);
    k3_finish<<<1, 64, 0, stream>>>(acc_out, out, 1.f / (float)N);
}

// Round 4
// 322.544 us; speedup vs baseline: 1.6421x; 1.6421x over previous
//
#include <hip/hip_runtime.h>
#include <hip/hip_bf16.h>
#include <math.h>

// Problem constants: N=100000, K=10, T=7, D=7, O=32
#define T_ 7
#define D_ 7
#define K_ 10
#define O_ 32
#define NPB 256           // nodes per block (== blockDim.x)
#define NREP 16           // replicated global accumulators (atomic spread)
#define NEG_SLOPE 0.01f

// async global->LDS DMA, 16B per lane. LDS dest: wave-uniform base, HW adds lane*16.
__device__ __forceinline__ void gl_lds16(const float4* g, float4* lds_wave_base) {
    __builtin_amdgcn_global_load_lds(
        (const __attribute__((address_space(1))) void*)g,
        (__attribute__((address_space(3))) void*)lds_wave_base,
        16, 0, 0);
}

// ---------------- K0: zero the replicated output accumulators --------------
__global__ void k0_zero(float* __restrict__ acc) {
    int i = threadIdx.x;
    if (i < NREP * O_) acc[i] = 0.f;
}

// ---------------- fused kernel --------------------------------------------
// One block = 256 nodes. Per t: barrier (prev readers done), issue ALL tile
// chunks via async global_load_lds (no VGPR round-trip, all in flight),
// barrier (drains vmcnt -> LDS visible), compute. h[56] in registers.
// Epilogue GEMM from LDS W_agg, sigmoid, wave reduce, replicated atomics.
__global__ __launch_bounds__(NPB) void k_fused(
    const float* __restrict__ xhet,   // [T,N,K,D]
    const float* __restrict__ xnode,  // [N,D]
    const int*   __restrict__ types,  // [N]
    const float* __restrict__ Wc,     // [T,D,D]
    const float* __restrict__ bc,     // [T,D]
    const float* __restrict__ Wagg,   // [O,56]
    const float* __restrict__ bagg,   // [O]
    float* __restrict__ acc_out,      // [NREP][O] global accumulators
    int N)
{
    __shared__ __align__(16) float tile[NPB * 70];   // 71680 B
    __shared__ float4 sW[O_ * 14];                   // 7168 B
    __shared__ float  sb[O_];
    __shared__ float  sacc[O_];
    // ~79 KB -> 2 blocks/CU (8 waves/CU)

    const int tx   = threadIdx.x;
    const int wv   = tx >> 6;         // wave id in block
    const int lane = tx & 63;
    const int nodeBase = blockIdx.x * NPB;
    const int n = nodeBase + tx;
    const bool active = (n < N);
    const int valid = min(NPB, N - nodeBase);
    const int L  = valid * 70;        // floats in this block's tile
    const int L4 = L >> 2;            // full float4 count

    // stage W_agg (1792 floats = 448 float4)
    for (int i = tx; i < O_ * 14; i += NPB) sW[i] = ((const float4*)Wagg)[i];
    if (tx < O_) { sb[tx] = bagg[tx]; sacc[tx] = 0.f; }

    // per-thread self inputs (tiny, cache-resident)
    float x[D_]; int tp = -1;
    if (active) {
        tp = types[n];
        #pragma unroll
        for (int d = 0; d < D_; ++d) x[d] = xnode[(size_t)n * D_ + d];
    } else {
        #pragma unroll
        for (int d = 0; d < D_; ++d) x[d] = 0.f;
    }

    float h[(T_ + 1) * D_];           // concat layout: h[t*7+o], self at 49..55
    #pragma unroll
    for (int j = 0; j < (T_ + 1) * D_; ++j) h[j] = 0.f;

    float4* tile4 = (float4*)tile;

    for (int t = 0; t < T_; ++t) {
        // block-uniform weights -> scalar regs
        float w[D_][D_], bias[D_];
        #pragma unroll
        for (int o = 0; o < D_; ++o) {
            bias[o] = bc[t * D_ + o];
            #pragma unroll
            for (int d = 0; d < D_; ++d) w[o][d] = Wc[(t * D_ + o) * D_ + d];
        }

        const float*  src  = xhet + ((size_t)t * N + nodeBase) * 70;
        const float4* src4 = (const float4*)src;     // 16B-aligned

        __syncthreads();   // previous iteration's readers done before overwrite

        // ---- issue ALL chunks async global->LDS (18 in flight per wave)
        // chunk j covers float4 indices [j*NPB, (j+1)*NPB); this wave's 64
        // lanes handle base+wv*64 .. base+wv*64+63, LDS dest = same indices.
        #pragma unroll
        for (int j = 0; j < 18; ++j) {               // ceil(4480/256)=18 when full
            const int i = j * NPB + wv * 64 + lane;  // == j*NPB + tx
            if (i < L4) gl_lds16(src4 + i, tile4 + j * NPB + wv * 64);
        }
        // rare scalar tail (only if L%4 != 0; impossible for even `valid`)
        for (int i = (L4 << 2) + tx; i < L; i += NPB) tile[i] = src[i];

        __syncthreads();   // drains vmcnt -> all async LDS writes visible

        if (active) {
            const float* myp = tile + tx * 70;
            float acc[D_] = {0.f, 0.f, 0.f, 0.f, 0.f, 0.f, 0.f};
            float cnt = 0.f;
            #pragma unroll
            for (int kk = 0; kk < K_ / 2; ++kk) {    // k in pairs: 14 floats = 7 float2
                float f[14];
                const float2* p2 = (const float2*)(myp + kk * 14);
                #pragma unroll
                for (int j = 0; j < 7; ++j) { float2 v = p2[j]; f[2*j] = v.x; f[2*j+1] = v.y; }
                #pragma unroll
                for (int hh = 0; hh < 2; ++hh) {
                    float pre[D_];
                    #pragma unroll
                    for (int o = 0; o < D_; ++o) pre[o] = bias[o];
                    #pragma unroll
                    for (int d = 0; d < D_; ++d) {
                        const float xv = f[hh * 7 + d];
                        #pragma unroll
                        for (int o = 0; o < D_; ++o) pre[o] = fmaf(xv, w[o][d], pre[o]);
                    }
                    bool nz = false;
                    #pragma unroll
                    for (int o = 0; o < D_; ++o) nz = nz || (pre[o] != 0.f);
                    cnt += nz ? 1.f : 0.f;
                    #pragma unroll
                    for (int o = 0; o < D_; ++o)
                        acc[o] += (pre[o] >= 0.f) ? pre[o] : NEG_SLOPE * pre[o];
                }
            }
            const float inv = 1.f / fmaxf(cnt, 1.f);
            #pragma unroll
            for (int o = 0; o < D_; ++o) h[t * D_ + o] = acc[o] * inv;

            // self candidate with this t's uniform weights; select on type match
            float ps[D_];
            #pragma unroll
            for (int o = 0; o < D_; ++o) {
                float p = bias[o];
                #pragma unroll
                for (int d = 0; d < D_; ++d) p = fmaf(x[d], w[o][d], p);
                ps[o] = (p >= 0.f) ? p : NEG_SLOPE * p;
            }
            if (tp == t) {
                #pragma unroll
                for (int o = 0; o < D_; ++o) h[T_ * D_ + o] = ps[o];
            }
        }
    }

    // ---- epilogue: [56] x [O,56]^T + bias -> sigmoid -> reduce
    #pragma unroll 4
    for (int o = 0; o < O_; ++o) {
        float s = sb[o];
        #pragma unroll
        for (int q = 0; q < 14; ++q) {
            float4 wv4 = sW[o * 14 + q];
            s += h[4*q] * wv4.x + h[4*q+1] * wv4.y + h[4*q+2] * wv4.z + h[4*q+3] * wv4.w;
        }
        float val = active ? 1.f / (1.f + __expf(-s)) : 0.f;
        #pragma unroll
        for (int off = 32; off >= 1; off >>= 1) val += __shfl_down(val, off);
        if (lane == 0) atomicAdd(&sacc[o], val);
    }
    __syncthreads();
    if (tx < O_) atomicAdd(acc_out + (blockIdx.x & (NREP - 1)) * O_ + tx, sacc[tx]);
}

// ---------------- K3: sum replicas, divide by N into d_out -----------------
__global__ void k3_finish(const float* __restrict__ acc, float* __restrict__ out, float invN) {
    int o = threadIdx.x;
    if (o < O_) {
        float s = 0.f;
        #pragma unroll
        for (int rr = 0; rr < NREP; ++rr) s += acc[rr * O_ + o];
        out[o] = s * invN;
    }
}

extern "C" void kernel_launch(void* const* d_in, const int* in_sizes, int n_in,
                              void* d_out, int out_size, void* d_ws, size_t ws_size,
                              hipStream_t stream) {
    const float* xnode = (const float*)d_in[0];   // [N,D]
    const float* xhet  = (const float*)d_in[1];   // [T,N,K,D]
    const int*   types = (const int*)d_in[2];     // [N]
    const float* Wc    = (const float*)d_in[3];   // [T,D,D]
    const float* bc    = (const float*)d_in[4];   // [T,D]
    const float* Wagg  = (const float*)d_in[5];   // [O,56]
    const float* bagg  = (const float*)d_in[6];   // [O]
    float* out = (float*)d_out;

    const int N = in_sizes[2];
    float* acc_out = (float*)d_ws;                // NREP*32 floats

    const int nblk = (N + NPB - 1) / NPB;

    k0_zero<<<1, 512, 0, stream>>>(acc_out);
    k_fused<<<nblk, NPB, 0, stream>>>(xhet, xnode, types, Wc, bc, Wagg, bagg, acc_out, N);
    k3_finish<<<1, 64, 0, stream>>>(acc_out, out, 1.f / (float)N);
}